// Round 1
// baseline (497.125 us; speedup 1.0000x reference)
//
#include <hip/hip_runtime.h>
#include <math.h>

#define BB 32
#define HH 16
#define DD 128
#define BSZ 16
#define MAXBLK 64
#define SMAX 1024
#define SCALE 0.08838834764831845f

// Write the new token's K/V into the paged caches (vLLM reshape_and_cache).
__global__ __launch_bounds__(256) void cache_write_kernel(
    const float* __restrict__ key, const float* __restrict__ value,
    float* __restrict__ kc, float* __restrict__ vc,
    const int* __restrict__ slot_mapping)
{
    int tid = blockIdx.x * 256 + threadIdx.x;      // 0 .. B*H*D-1
    int b = tid >> 11;                             // / (H*D)=2048
    int r = tid & 2047;
    int h = r >> 7;
    int d = r & 127;
    int slot = slot_mapping[b];
    int blk = slot >> 4;
    int pos = slot & 15;
    size_t base = ((size_t)blk * HH + h) * 2048;
    // key_cache [NB,H,D/8,BS,8]
    kc[base + (size_t)(d >> 3) * 128 + pos * 8 + (d & 7)] = key[tid];
    // value_cache [NB,H,BS,D]
    vc[base + (size_t)pos * 128 + d] = value[tid];
}

// One workgroup (256 thr = 4 waves) per (b,h).
__global__ __launch_bounds__(256) void attn_kernel(
    const float* __restrict__ q, const float* __restrict__ kc,
    const float* __restrict__ vc, const int* __restrict__ block_tables,
    const int* __restrict__ context_lens, float* __restrict__ out)
{
    __shared__ float s_scores[SMAX];
    __shared__ float s_q[DD];
    __shared__ float s_red[8];
    __shared__ float s_out[4][DD];

    int bh   = blockIdx.x;
    int b    = bh >> 4;
    int h    = bh & 15;
    int tid  = threadIdx.x;
    int wave = tid >> 6;
    int lane = tid & 63;

    int len  = context_lens[b];
    int nblk = (len + 15) >> 4;

    if (tid < DD) s_q[tid] = q[(size_t)bh * DD + tid] * SCALE;
    __syncthreads();

    // Each lane preloads the 16 q-pairs it needs (d_lo = 2*(lane&3), +1).
    int dlo = 2 * (lane & 3);
    float2 rq[16];
#pragma unroll
    for (int dh = 0; dh < 16; ++dh)
        rq[dh] = *(const float2*)&s_q[dh * 8 + dlo];

    const int* bt = block_tables + b * MAXBLK;

    // ---- Phase 1: scores. K block layout per (pb,h): [d_hi=16][tok=16][x=8].
    for (int cb = wave; cb < nblk; cb += 4) {
        int pb = bt[cb];
        const float* kbase = kc + ((size_t)pb * HH + h) * 2048 + 2 * lane;
        float acc = 0.f;
#pragma unroll
        for (int dh = 0; dh < 16; ++dh) {
            float2 kv = *(const float2*)(kbase + dh * 128);
            acc += rq[dh].x * kv.x + rq[dh].y * kv.y;
        }
        // lanes 4t..4t+3 hold partials of token t
        acc += __shfl_xor(acc, 1);
        acc += __shfl_xor(acc, 2);
        if ((lane & 3) == 0) {
            int p = cb * 16 + (lane >> 2);
            s_scores[p] = (p < len) ? acc : -INFINITY;
        }
    }
    __syncthreads();

    int padded = nblk * 16;

    // ---- Phase 2: softmax (max, exp, sum) over s_scores[0..padded)
    float m = -INFINITY;
    for (int p = tid; p < padded; p += 256) m = fmaxf(m, s_scores[p]);
#pragma unroll
    for (int off = 32; off; off >>= 1) m = fmaxf(m, __shfl_xor(m, off));
    if (lane == 0) s_red[wave] = m;
    __syncthreads();
    m = fmaxf(fmaxf(s_red[0], s_red[1]), fmaxf(s_red[2], s_red[3]));

    float sum = 0.f;
    for (int p = tid; p < padded; p += 256) {
        float e = __expf(s_scores[p] - m);
        s_scores[p] = e;
        sum += e;
    }
#pragma unroll
    for (int off = 32; off; off >>= 1) sum += __shfl_xor(sum, off);
    if (lane == 0) s_red[4 + wave] = sum;
    __syncthreads();
    float inv = 1.f / (s_red[4] + s_red[5] + s_red[6] + s_red[7]);

    // ---- Phase 3: out = sum_p attn[p] * V[p,:]. V row = 128 contiguous f32.
    float2 acc2 = make_float2(0.f, 0.f);
    for (int cb = wave; cb < nblk; cb += 4) {
        int pb = bt[cb];
        const float* vbase = vc + ((size_t)pb * HH + h) * 2048 + 2 * lane;
#pragma unroll
        for (int t = 0; t < 16; ++t) {
            float w = s_scores[cb * 16 + t];   // 0 for padded tokens
            float2 vv = *(const float2*)(vbase + t * 128);
            acc2.x += w * vv.x;
            acc2.y += w * vv.y;
        }
    }
    s_out[wave][2 * lane]     = acc2.x;
    s_out[wave][2 * lane + 1] = acc2.y;
    __syncthreads();

    if (tid < DD) {
        float o = (s_out[0][tid] + s_out[1][tid] + s_out[2][tid] + s_out[3][tid]) * inv;
        out[(size_t)bh * DD + tid] = o;
    }
}

extern "C" void kernel_launch(void* const* d_in, const int* in_sizes, int n_in,
                              void* d_out, int out_size, void* d_ws, size_t ws_size,
                              hipStream_t stream) {
    const float* query        = (const float*)d_in[0];
    const float* key          = (const float*)d_in[1];
    const float* value        = (const float*)d_in[2];
    float*       key_cache    = (float*)d_in[3];
    float*       value_cache  = (float*)d_in[4];
    const int*   block_tables = (const int*)d_in[5];
    const int*   context_lens = (const int*)d_in[6];
    const int*   slot_mapping = (const int*)d_in[7];
    float*       out          = (float*)d_out;

    cache_write_kernel<<<(BB * HH * DD) / 256, 256, 0, stream>>>(
        key, value, key_cache, value_cache, slot_mapping);
    attn_kernel<<<BB * HH, 256, 0, stream>>>(
        query, key_cache, value_cache, block_tables, context_lens, out);
}

// Round 2
// 492.646 us; speedup vs baseline: 1.0091x; 1.0091x over previous
//
#include <hip/hip_runtime.h>
#include <math.h>

#define BB 32
#define HH 16
#define DD 128
#define BSZ 16
#define MAXBLK 64
#define NCHUNK 4      // chunks per (b,h); 4 * 256 = 1024 = max context
#define CT 256        // tokens per chunk
#define CBLK 16       // paged blocks per chunk
#define SCALE 0.08838834764831845f

// Flash-decode chunk kernel: one workgroup (4 waves) per (b, h, chunk).
// Computes unnormalized partial output o_c, local max m_c, local exp-sum l_c.
// The new token (position len-1) is folded in from new_k/new_v inline —
// the paged caches are never mutated.
__global__ __launch_bounds__(256) void attn_chunk_kernel(
    const float* __restrict__ q, const float* __restrict__ newk,
    const float* __restrict__ newv, const float* __restrict__ kc,
    const float* __restrict__ vc, const int* __restrict__ block_tables,
    const int* __restrict__ context_lens,
    float* __restrict__ o_part, float* __restrict__ m_part,
    float* __restrict__ l_part)
{
    __shared__ float s_scores[CT];
    __shared__ float s_q[DD];
    __shared__ float s_red[8];
    __shared__ float s_out[4][DD];

    int gid  = blockIdx.x;         // bh * NCHUNK + c
    int c    = gid & (NCHUNK - 1);
    int bh   = gid >> 2;
    int b    = bh >> 4;
    int h    = bh & 15;
    int tid  = threadIdx.x;
    int wave = tid >> 6;
    int lane = tid & 63;

    int len    = context_lens[b];
    int cstart = c * CT;
    if (cstart >= len) return;     // chunk entirely beyond context

    int nblk   = (len + 15) >> 4;
    int cb0    = c * CBLK;
    int cb_end = min(nblk, cb0 + CBLK);
    int last   = len - 1;
    bool haslast = (last >> 8) == c;   // this chunk holds the new token

    if (tid < DD) s_q[tid] = q[(size_t)bh * DD + tid] * SCALE;
    __syncthreads();

    // Each lane preloads the 16 q-pairs it needs (d_lo = 2*(lane&3), +1).
    int dlo = 2 * (lane & 3);
    float2 rq[16];
#pragma unroll
    for (int dh = 0; dh < 16; ++dh)
        rq[dh] = *(const float2*)&s_q[dh * 8 + dlo];

    const int* bt = block_tables + b * MAXBLK;

    // ---- Phase 1: scores. K block layout per (pb,h): [d_hi=16][tok=16][x=8].
    for (int cb = cb0 + wave; cb < cb_end; cb += 4) {
        int pb = bt[cb];
        const float* kbase = kc + ((size_t)pb * HH + h) * 2048 + 2 * lane;
        float acc = 0.f;
#pragma unroll
        for (int dh = 0; dh < 16; ++dh) {
            float2 kv = *(const float2*)(kbase + dh * 128);
            acc += rq[dh].x * kv.x + rq[dh].y * kv.y;
        }
        acc += __shfl_xor(acc, 1);
        acc += __shfl_xor(acc, 2);
        if ((lane & 3) == 0) {
            int t = lane >> 2;
            int p = cb * 16 + t;
            s_scores[(cb - cb0) * 16 + t] = (p < len) ? acc : -INFINITY;
        }
    }
    __syncthreads();

    // ---- New-token score fix: recompute score at `last` from new_k.
    if (haslast && wave == 0) {
        float2 nk = *(const float2*)&newk[(size_t)bh * DD + 2 * lane];
        float part = s_q[2 * lane] * nk.x + s_q[2 * lane + 1] * nk.y;
#pragma unroll
        for (int off = 32; off; off >>= 1) part += __shfl_xor(part, off);
        if (lane == 0) s_scores[last - cstart] = part;
    }
    __syncthreads();

    // ---- Phase 2: local softmax over padded = (cb_end-cb0)*16 entries.
    int padded = (cb_end - cb0) * 16;
    float mloc = (tid < padded) ? s_scores[tid] : -INFINITY;
#pragma unroll
    for (int off = 32; off; off >>= 1) mloc = fmaxf(mloc, __shfl_xor(mloc, off));
    if (lane == 0) s_red[wave] = mloc;
    __syncthreads();
    float m = fmaxf(fmaxf(s_red[0], s_red[1]), fmaxf(s_red[2], s_red[3]));

    float e = 0.f;
    if (tid < padded) {
        e = __expf(s_scores[tid] - m);
        s_scores[tid] = e;              // unnormalized weights
    }
    float ssum = e;
#pragma unroll
    for (int off = 32; off; off >>= 1) ssum += __shfl_xor(ssum, off);
    if (lane == 0) s_red[4 + wave] = ssum;
    __syncthreads();
    float lsum = s_red[4] + s_red[5] + s_red[6] + s_red[7];

    // ---- Phase 3: o_c = sum_p e[p] * V[p,:]. V row = 128 contiguous f32.
    float2 nv2 = make_float2(0.f, 0.f);
    if (haslast) nv2 = *(const float2*)&newv[(size_t)bh * DD + 2 * lane];
    int lastLocal = haslast ? last : -1;

    float2 acc2 = make_float2(0.f, 0.f);
    for (int cb = cb0 + wave; cb < cb_end; cb += 4) {
        int pb = bt[cb];
        const float* vbase = vc + ((size_t)pb * HH + h) * 2048 + 2 * lane;
#pragma unroll
        for (int t = 0; t < 16; ++t) {
            float w = s_scores[(cb - cb0) * 16 + t];   // 0 for masked tokens
            float2 vv = *(const float2*)(vbase + t * 128);
            if (cb * 16 + t == lastLocal) vv = nv2;
            acc2.x += w * vv.x;
            acc2.y += w * vv.y;
        }
    }
    s_out[wave][2 * lane]     = acc2.x;
    s_out[wave][2 * lane + 1] = acc2.y;
    __syncthreads();

    if (tid < DD) {
        float o = s_out[0][tid] + s_out[1][tid] + s_out[2][tid] + s_out[3][tid];
        o_part[(size_t)gid * DD + tid] = o;
    }
    if (tid == 0) {
        m_part[gid] = m;
        l_part[gid] = lsum;
    }
}

// Log-sum-exp merge of the per-chunk partials. One block (2 waves) per (b,h).
__global__ __launch_bounds__(128) void attn_combine_kernel(
    const float* __restrict__ o_part, const float* __restrict__ m_part,
    const float* __restrict__ l_part, const int* __restrict__ context_lens,
    float* __restrict__ out)
{
    int bh  = blockIdx.x;
    int b   = bh >> 4;
    int tid = threadIdx.x;
    int len = context_lens[b];
    int nc  = (len + CT - 1) >> 8;

    float mi[NCHUNK];
    float m_g = -INFINITY;
    for (int i = 0; i < nc; ++i) {
        mi[i] = m_part[bh * NCHUNK + i];
        m_g = fmaxf(m_g, mi[i]);
    }
    float acc = 0.f, lg = 0.f;
    for (int i = 0; i < nc; ++i) {
        float w = __expf(mi[i] - m_g);
        lg  += w * l_part[bh * NCHUNK + i];
        acc += w * o_part[(size_t)(bh * NCHUNK + i) * DD + tid];
    }
    out[(size_t)bh * DD + tid] = acc / lg;
}

extern "C" void kernel_launch(void* const* d_in, const int* in_sizes, int n_in,
                              void* d_out, int out_size, void* d_ws, size_t ws_size,
                              hipStream_t stream) {
    const float* query        = (const float*)d_in[0];
    const float* key          = (const float*)d_in[1];
    const float* value        = (const float*)d_in[2];
    const float* key_cache    = (const float*)d_in[3];
    const float* value_cache  = (const float*)d_in[4];
    const int*   block_tables = (const int*)d_in[5];
    const int*   context_lens = (const int*)d_in[6];
    float*       out          = (float*)d_out;

    // Workspace layout: o_part [B*H*NCHUNK, 128] | m_part | l_part
    float* o_part = (float*)d_ws;
    float* m_part = o_part + (size_t)BB * HH * NCHUNK * DD;
    float* l_part = m_part + (size_t)BB * HH * NCHUNK;

    attn_chunk_kernel<<<BB * HH * NCHUNK, 256, 0, stream>>>(
        query, key, value, key_cache, value_cache, block_tables,
        context_lens, o_part, m_part, l_part);
    attn_combine_kernel<<<BB * HH, 128, 0, stream>>>(
        o_part, m_part, l_part, context_lens, out);
}